// Round 10
// baseline (132.439 us; speedup 1.0000x reference)
//
#include <hip/hip_runtime.h>
#include <hip/hip_bf16.h>
#include <math.h>

// Problem constants (from reference setup_inputs)
#define NPTS   65536
#define NGT    256
#define NCLS   80
#define TOPK   9
#define GSLICE 32                 // gts per filter block (grid.y = 8)
#define NPB    256                // points per filter block (grid.x = 256)
#define NXB    (NPTS / NPB)       // 256 point-chunks
#define SCAP   64                 // fixed per-(gt,chunk) bucket segment size
#define NSUB   4                  // select1 blocks per gt
#define NWV    16                 // partial lists per gt (4 blocks x 4 waves)

// Workspace layout (no global atomics — rounds 3-5: 65K same-line global
// atomicAdds serialize at L2 for ~23 us):
//   bucket : [NGT][NXB][SCAP] u64 = 33.55 MB (deterministic slot ranges,
//            FINAL rank keys — scoring fused into filter's copy-out)
//   counts : [NGT][NXB]       u16 = 128 KB   (written unconditionally)
//   partial: [NGT][NWV][TOPK] u64 = 288 KB   (per-wave top-9)
//
// Rank key: (sortable bits of L) << 32 | ~point_idx with
// L = 0.2*log2(sigmoid(cls)) + 0.8*log2(iou) — monotone transform of the
// reference score sigmoid^.2 * iou^.8, verified absmax 0.0 in rounds 1-9.
// u64-max == (higher score, lower index) == JAX top_k tie-break. Keys are
// unique within a gt (embed ~point_idx) -> pop-argmax owners unique. All
// real and filler keys are > 0 (k32 >= 0x00800000 for finite L; filler
// -inf -> 0x007FFFFF...), so 0 is the natural "empty" value.
__device__ inline unsigned long long pack_key(float L, unsigned idx) {
    unsigned u   = __float_as_uint(L);
    unsigned k32 = (u & 0x80000000u) ? ~u : (u | 0x80000000u);
    return ((unsigned long long)k32 << 32) | (unsigned)(~idx);
}

__device__ inline unsigned long long umax64(unsigned long long a,
                                            unsigned long long b) {
    return a > b ? a : b;
}

__device__ inline unsigned long long wave_max64(unsigned long long m) {
#pragma unroll
    for (int off = 1; off < 64; off <<= 1)
        m = umax64(m, (unsigned long long)__shfl_xor((long long)m, off));
    return m;
}

// ---------------------------------------------------------------------------
// k1: filter + score + compact into deterministic per-(gt,chunk) segments.
// Bit-identical to rounds 8-9 (verified absmax 0.0). Also zeroes w.
// ---------------------------------------------------------------------------
__global__ __launch_bounds__(256) void filter_kernel(
    const float* __restrict__ preds,          // [NPTS][4]
    const float* __restrict__ gtb,            // [NGT][4]
    const int*   __restrict__ glab,           // [NGT]
    const float* __restrict__ cls,            // [NPTS][NCLS]
    unsigned short* __restrict__ counts,      // [NGT][NXB]
    unsigned long long* __restrict__ bucket,  // [NGT][NXB][SCAP]
    float* __restrict__ w)                    // [NPTS]
{
    __shared__ unsigned lcnt[GSLICE];
    __shared__ int      glabs[GSLICE];
    __shared__ unsigned long long stage[GSLICE][SCAP]; // 16 KiB

    const int t   = threadIdx.x;
    const int xb  = blockIdx.x;                 // point chunk 0..255
    const int g0  = blockIdx.y * GSLICE;
    const int pt  = xb * NPB + t;
    const int bid = blockIdx.y * NXB + xb;      // 0..2047

    if (t < GSLICE) {
        lcnt[t]  = 0u;
        glabs[t] = glab[g0 + t];
    }
    if (t < 32) w[bid * 32 + t] = 0.0f;         // 2048 blocks x 32 = NPTS

    float4 pb = ((const float4*)preds)[pt];
    float parea = (pb.z - pb.x) * (pb.w - pb.y);
    __syncthreads();

    for (int gi = 0; gi < GSLICE; ++gi) {
        const float4 g4 = ((const float4*)gtb)[g0 + gi];  // uniform -> SGPR
        float ix1 = fmaxf(pb.x, g4.x), iy1 = fmaxf(pb.y, g4.y);
        float ix2 = fminf(pb.z, g4.z), iy2 = fminf(pb.w, g4.w);
        float iw  = fmaxf(ix2 - ix1, 0.0f);
        float ih  = fmaxf(iy2 - iy1, 0.0f);
        float inter = iw * ih;
        if (inter > 0.0f) {
            // bit-exact round-1 operand forms
            float garea = (g4.z - g4.x) * (g4.w - g4.y);
            float uni = fmaxf(parea + garea - inter, 1e-6f);
            float iou = inter / uni;
            unsigned long long entry =
                ((unsigned long long)__float_as_uint(iou) << 32) |
                (unsigned)(~(unsigned)pt);
            unsigned slot = atomicAdd(&lcnt[gi], 1u);   // LDS atomic only
            if (slot < SCAP) stage[gi][slot] = entry;
            // slot >= SCAP statistically unreachable (P ~ 2.5e-12/pair,
            // fixed input seed; never hit in rounds 1-9)
        }
    }
    __syncthreads();

    if (t < GSLICE) {
        unsigned c = lcnt[t];
        if (c > SCAP) c = SCAP;
        lcnt[t] = c;
        counts[(size_t)(g0 + t) * NXB + xb] = (unsigned short)c;
    }
    __syncthreads();

    // scoring copy-out: gathers + transcendentals only on the ~366 real
    // entries (exec-masked) — round 7 showed dense scoring is fatal.
    const float E1 = 1.0f - 0.8f;   // exact round-1 constant expression
#pragma unroll
    for (int k = 0; k < 8; k += 4) {
        unsigned long long e[4];
        bool  vld[4];
        int   gi[4];
        float x[4];
#pragma unroll
        for (int j = 0; j < 4; ++j) {
            int i = (k + j) * 256 + t;
            gi[j] = i >> 6;                 // uniform per wave
            int sl = i & (SCAP - 1);        // == lane
            e[j]   = stage[gi[j]][sl];
            vld[j] = sl < (int)lcnt[gi[j]];
        }
#pragma unroll
        for (int j = 0; j < 4; ++j) {
            if (vld[j]) {                   // exec-masked: no addr otherwise
                unsigned p = ~(unsigned)(e[j] & 0xFFFFFFFFu);
                x[j] = cls[(size_t)p * NCLS + glabs[gi[j]]];
            }
        }
#pragma unroll
        for (int j = 0; j < 4; ++j) {
            if (vld[j]) {
                float iou = __uint_as_float((unsigned)(e[j] >> 32));
                float s   = 1.0f / (1.0f + expf(-x[j]));
                float L   = E1 * log2f(s) + 0.8f * log2f(iou);
                unsigned u   = __float_as_uint(L);
                unsigned k32 = (u & 0x80000000u) ? ~u : (u | 0x80000000u);
                int i = (k + j) * 256 + t;
                bucket[((size_t)(g0 + gi[j]) * NXB + xb) * SCAP + (i & (SCAP - 1))]
                    = ((unsigned long long)k32 << 32) | (e[j] & 0xFFFFFFFFu);
            }
        }
    }
}

// ---------------------------------------------------------------------------
// k2a: per (gt, quarter): BARRIER-FREE per-wave top-9. Each wave scans 1024
// slots; segment counts are wave-uniform (segment = strip*4 + wave) ->
// scalar load, validity = (lane < c): 2 VALU. Then a 9-round 64-lane
// butterfly pop-argmax (no __syncthreads anywhere — round 9's version paid
// 18 full 16-wave barriers). Writes 9 keys/wave to partial.
// ---------------------------------------------------------------------------
__global__ __launch_bounds__(256) void select1_kernel(
    const unsigned short*     __restrict__ counts,  // [NGT][NXB]
    const unsigned long long* __restrict__ bucket,  // [NGT][NXB][SCAP]
    unsigned long long*       __restrict__ partial) // [NGT][NWV][TOPK]
{
    const int g    = blockIdx.x;
    const int sub  = blockIdx.y;                // 0..3
    const int t    = threadIdx.x;
    const int lane = t & 63;
    const int wv   = t >> 6;                    // 0..3

    const unsigned long long* src =
        bucket + (size_t)g * (NXB * SCAP) + (size_t)sub * 4096;
    const unsigned short* cnt = counts + (size_t)g * NXB + sub * 64;

    // scan 16 slots/thread; slot (k*256 + t) -> segment k*4 + wv (uniform)
    unsigned long long e[16];
#pragma unroll
    for (int k = 0; k < 16; k += 4) {
        unsigned long long v[4];
#pragma unroll
        for (int j = 0; j < 4; ++j) v[j] = src[(k + j) * 256 + t];
#pragma unroll
        for (int j = 0; j < 4; ++j) {
            int c = (int)cnt[(k + j) * 4 + wv];   // wave-uniform -> scalar
            e[k + j] = (lane < c) ? v[j] : 0ULL;  // poison masked
        }
    }
    unsigned long long mymax = 0ULL;
#pragma unroll
    for (int j = 0; j < 16; ++j) mymax = umax64(mymax, e[j]);

    unsigned long long out[TOPK];
#pragma unroll
    for (int r = 0; r < TOPK; ++r) {
        unsigned long long m = wave_max64(mymax);
        out[r] = m;
        if (m != 0ULL && mymax == m) {      // unique owner pops
#pragma unroll
            for (int j = 0; j < 16; ++j) if (e[j] == m) e[j] = 0ULL;
            mymax = 0ULL;
#pragma unroll
            for (int j = 0; j < 16; ++j) mymax = umax64(mymax, e[j]);
        }
    }
    if (lane == 0) {
        unsigned long long* dst =
            partial + ((size_t)g * NWV + (size_t)(sub * 4 + wv)) * TOPK;
#pragma unroll
        for (int r = 0; r < TOPK; ++r) dst[r] = out[r];
    }
}

// ---------------------------------------------------------------------------
// k2b: per gt, ONE wave: top-9 of the 144 partial keys + the 9 filler keys
// (-inf, idx 0..8 — candidate pool bit-identical to rounds 1-9), 9-round
// single-wave pop-argmax, then the verified Gaussian / validity / atomicMax
// tail (bit-identical to rounds 1-9, absmax 0.0).
// ---------------------------------------------------------------------------
__global__ __launch_bounds__(64) void select2_kernel(
    const unsigned long long* __restrict__ partial, // [NGT][NWV][TOPK]
    const float* __restrict__ pts,                  // [NPTS][2]
    const float* __restrict__ gtb,                  // [NGT][4]
    float* __restrict__ w)                          // [NPTS]
{
    const int g = blockIdx.x;
    const int t = threadIdx.x;                      // 0..63

    __shared__ float ppy[TOPK], ppx[TOPK];
    __shared__ unsigned tidx_s[TOPK];

    const unsigned long long* src = partial + (size_t)g * (NWV * TOPK); // 144
    unsigned long long e[4];
    e[0] = src[t];
    e[1] = src[64 + t];
    e[2] = (t < NWV * TOPK - 128) ? src[128 + t] : 0ULL;   // 16 keys
    e[3] = (t < TOPK) ? pack_key(-INFINITY, (unsigned)t) : 0ULL;

    unsigned long long mymax = 0ULL;
#pragma unroll
    for (int j = 0; j < 4; ++j) mymax = umax64(mymax, e[j]);

#pragma unroll
    for (int r = 0; r < TOPK; ++r) {
        unsigned long long m = wave_max64(mymax);   // >0: fillers guarantee 9
        if (t == 0) tidx_s[r] = ~(unsigned)(m & 0xFFFFFFFFu);
        if (mymax == m) {                           // unique owner pops
#pragma unroll
            for (int j = 0; j < 4; ++j) if (e[j] == m) e[j] = 0ULL;
            mymax = 0ULL;
#pragma unroll
            for (int j = 0; j < 4; ++j) mymax = umax64(mymax, e[j]);
        }
    }
    __syncthreads();

    if (t < TOPK) {
        unsigned pi = tidx_s[t];
        ppy[t] = pts[2 * (size_t)pi];       // points col 0 ("cy" in reference)
        ppx[t] = pts[2 * (size_t)pi + 1];   // points col 1 ("cx")
    }
    __syncthreads();

    if (t == 0) {
        float4 g4 = ((const float4*)gtb)[g];
        float m0 = 0.0f, m1 = 0.0f;
#pragma unroll
        for (int k = 0; k < TOPK; ++k) { m0 += ppy[k]; m1 += ppx[k]; }
        m0 /= (float)TOPK; m1 /= (float)TOPK;

        float d0[TOPK], d1[TOPK];
        float a = 0.0f, bb = 0.0f, dd = 0.0f;
#pragma unroll
        for (int k = 0; k < TOPK; ++k) {
            d0[k] = ppy[k] - m0;
            d1[k] = ppx[k] - m1;
            a  += d0[k] * d0[k];
            bb += d0[k] * d1[k];
            dd += d1[k] * d1[k];
        }
        a /= (float)TOPK; bb /= (float)TOPK; dd /= (float)TOPK;
        float det  = a * dd - bb * bb;
        float rinv = 1.0f / (det + 1e-10f);

#pragma unroll
        for (int k = 0; k < TOPK; ++k) {
            float q = d0[k] * (dd * d0[k] - bb * d1[k])
                    + d1[k] * (a  * d1[k] - bb * d0[k]);
            float maha = q * rinv;
            float wt = expf(-0.5f * maha);
            bool valid = (ppx[k] - g4.x > 1e-10f) && (ppy[k] - g4.y > 1e-10f) &&
                         (g4.z - ppx[k] > 1e-10f) && (g4.w - ppy[k] > 1e-10f);
            float wv = valid ? wt : 0.0f;
            atomicMax((int*)&w[tidx_s[k]], __float_as_int(wv));
        }
    }
}

// ---------------------------------------------------------------------------
extern "C" void kernel_launch(void* const* d_in, const int* in_sizes, int n_in,
                              void* d_out, int out_size, void* d_ws, size_t ws_size,
                              hipStream_t stream) {
    const float* points  = (const float*)d_in[0];   // [65536,2]
    const float* cls     = (const float*)d_in[1];   // [65536,80]
    const float* preds   = (const float*)d_in[2];   // [65536,4]
    const float* gtb     = (const float*)d_in[3];   // [256,4]
    const int*   glab    = (const int*)d_in[4];     // [256]
    float* w = (float*)d_out;                       // [65536] f32

    char* ws = (char*)d_ws;
    unsigned long long* bucket = (unsigned long long*)ws;          // 33.55 MB
    size_t off = (size_t)NGT * NXB * SCAP * sizeof(unsigned long long);
    unsigned short* counts = (unsigned short*)(ws + off);          // 128 KB
    off += (size_t)NGT * NXB * sizeof(unsigned short);
    unsigned long long* partial = (unsigned long long*)(ws + off); // 288 KB

    filter_kernel<<<dim3(NXB, NGT / GSLICE), 256, 0, stream>>>(
        preds, gtb, glab, cls, counts, bucket, w);
    select1_kernel<<<dim3(NGT, NSUB), 256, 0, stream>>>(counts, bucket, partial);
    select2_kernel<<<NGT, 64, 0, stream>>>(partial, points, gtb, w);
}

// Round 11
// 114.580 us; speedup vs baseline: 1.1559x; 1.1559x over previous
//
#include <hip/hip_runtime.h>
#include <hip/hip_bf16.h>
#include <math.h>

// Problem constants (from reference setup_inputs)
#define NPTS   65536
#define NGT    256
#define NCLS   80
#define TOPK   9
#define GSLICE 32                 // gts per filter block (grid.y = 8)
#define NPB    256                // points per filter block (grid.x = 256)
#define NXB    (NPTS / NPB)       // 256 point-chunks
#define SCAP   64                 // fixed per-(gt,chunk) bucket segment size

// Workspace layout (no global atomics — rounds 3-5: 65K same-line global
// atomicAdds serialize at L2 for ~23 us):
//   bucket : [NGT][NXB][SCAP] u64 = 33.55 MB (deterministic slot ranges,
//            FINAL rank keys — scoring fused into filter's copy-out)
//   counts : [NGT][NXB]       u16 = 128 KB   (written unconditionally)
//
// Rank key: (sortable bits of L) << 32 | ~point_idx with
// L = 0.2*log2(sigmoid(cls)) + 0.8*log2(iou) — monotone transform of the
// reference score sigmoid^.2 * iou^.8, verified absmax 0.0 in rounds 1-10.
// u64-max == (higher score, lower index) == JAX top_k tie-break. Keys are
// unique within a gt (embed ~point_idx) -> pop-argmax owners unique; all
// real/filler keys > 0, so 0 is the natural "empty".
//
// DISPATCH-COUNT LESSON (R10): every 3-dispatch config lands 129-134
// regardless of kernel content; best 2-dispatch (R9) = 112.8. The graph
// node boundary costs ~15-20 us here — never add a dispatch to save less.
__device__ inline unsigned long long pack_key(float L, unsigned idx) {
    unsigned u   = __float_as_uint(L);
    unsigned k32 = (u & 0x80000000u) ? ~u : (u | 0x80000000u);
    return ((unsigned long long)k32 << 32) | (unsigned)(~idx);
}

__device__ inline unsigned long long umax64(unsigned long long a,
                                            unsigned long long b) {
    return a > b ? a : b;
}

__device__ inline unsigned long long wave_max64(unsigned long long m) {
#pragma unroll
    for (int off = 1; off < 64; off <<= 1)
        m = umax64(m, (unsigned long long)__shfl_xor(m, off));
    return m;
}

// ---------------------------------------------------------------------------
// k1: filter + score + compact into deterministic per-(gt,chunk) segments.
// Bit-identical to rounds 8-10 (verified absmax 0.0). Also zeroes w.
// ---------------------------------------------------------------------------
__global__ __launch_bounds__(256) void filter_kernel(
    const float* __restrict__ preds,          // [NPTS][4]
    const float* __restrict__ gtb,            // [NGT][4]
    const int*   __restrict__ glab,           // [NGT]
    const float* __restrict__ cls,            // [NPTS][NCLS]
    unsigned short* __restrict__ counts,      // [NGT][NXB]
    unsigned long long* __restrict__ bucket,  // [NGT][NXB][SCAP]
    float* __restrict__ w)                    // [NPTS]
{
    __shared__ unsigned lcnt[GSLICE];
    __shared__ int      glabs[GSLICE];
    __shared__ unsigned long long stage[GSLICE][SCAP]; // 16 KiB

    const int t   = threadIdx.x;
    const int xb  = blockIdx.x;                 // point chunk 0..255
    const int g0  = blockIdx.y * GSLICE;
    const int pt  = xb * NPB + t;
    const int bid = blockIdx.y * NXB + xb;      // 0..2047

    if (t < GSLICE) {
        lcnt[t]  = 0u;
        glabs[t] = glab[g0 + t];
    }
    if (t < 32) w[bid * 32 + t] = 0.0f;         // 2048 blocks x 32 = NPTS

    float4 pb = ((const float4*)preds)[pt];
    float parea = (pb.z - pb.x) * (pb.w - pb.y);
    __syncthreads();

    for (int gi = 0; gi < GSLICE; ++gi) {
        const float4 g4 = ((const float4*)gtb)[g0 + gi];  // uniform -> SGPR
        float ix1 = fmaxf(pb.x, g4.x), iy1 = fmaxf(pb.y, g4.y);
        float ix2 = fminf(pb.z, g4.z), iy2 = fminf(pb.w, g4.w);
        float iw  = fmaxf(ix2 - ix1, 0.0f);
        float ih  = fmaxf(iy2 - iy1, 0.0f);
        float inter = iw * ih;
        if (inter > 0.0f) {
            // bit-exact round-1 operand forms
            float garea = (g4.z - g4.x) * (g4.w - g4.y);
            float uni = fmaxf(parea + garea - inter, 1e-6f);
            float iou = inter / uni;
            unsigned long long entry =
                ((unsigned long long)__float_as_uint(iou) << 32) |
                (unsigned)(~(unsigned)pt);
            unsigned slot = atomicAdd(&lcnt[gi], 1u);   // LDS atomic only
            if (slot < SCAP) stage[gi][slot] = entry;
            // slot >= SCAP statistically unreachable (P ~ 2.5e-12/pair,
            // fixed input seed; never hit in rounds 1-10)
        }
    }
    __syncthreads();

    if (t < GSLICE) {
        unsigned c = lcnt[t];
        if (c > SCAP) c = SCAP;
        lcnt[t] = c;
        counts[(size_t)(g0 + t) * NXB + xb] = (unsigned short)c;
    }
    __syncthreads();

    // scoring copy-out: gathers + transcendentals only on the ~366 real
    // entries (exec-masked) — round 7 showed dense scoring is fatal.
    const float E1 = 1.0f - 0.8f;   // exact round-1 constant expression
#pragma unroll
    for (int k = 0; k < 8; k += 4) {
        unsigned long long e[4];
        bool  vld[4];
        int   gi[4];
        float x[4];
#pragma unroll
        for (int j = 0; j < 4; ++j) {
            int i = (k + j) * 256 + t;
            gi[j] = i >> 6;                 // uniform per wave
            int sl = i & (SCAP - 1);        // == lane
            e[j]   = stage[gi[j]][sl];
            vld[j] = sl < (int)lcnt[gi[j]];
        }
#pragma unroll
        for (int j = 0; j < 4; ++j) {
            if (vld[j]) {                   // exec-masked: no addr otherwise
                unsigned p = ~(unsigned)(e[j] & 0xFFFFFFFFu);
                x[j] = cls[(size_t)p * NCLS + glabs[gi[j]]];
            }
        }
#pragma unroll
        for (int j = 0; j < 4; ++j) {
            if (vld[j]) {
                float iou = __uint_as_float((unsigned)(e[j] >> 32));
                float s   = 1.0f / (1.0f + expf(-x[j]));
                float L   = E1 * log2f(s) + 0.8f * log2f(iou);
                unsigned u   = __float_as_uint(L);
                unsigned k32 = (u & 0x80000000u) ? ~u : (u | 0x80000000u);
                int i = (k + j) * 256 + t;
                bucket[((size_t)(g0 + gi[j]) * NXB + xb) * SCAP + (i & (SCAP - 1))]
                    = ((unsigned long long)k32 << 32) | (e[j] & 0xFFFFFFFFu);
            }
        }
    }
}

// ---------------------------------------------------------------------------
// k2: per gt (1024 threads, 16 waves), R10's algorithm in R9's 2-dispatch
// shell. Phase A (barrier-free): wave w scans its contiguous 8 KB slice
// (slot = w*1024 + k*64 + lane -> segment w*16+k is wave-uniform, validity
// = lane < c), then a per-wave 9-round 64-lane butterfly pop-argmax; lane 0
// streams winners to LDS. ONE barrier. Phase B: wave 0 merges 144 partials
// + 9 filler keys (-inf, idx 0..8 — pool bit-identical to rounds 1-10)
// with a single-wave pop-argmax. Then the verified Gaussian/atomicMax tail.
// 4 barriers total vs round 9's ~21 (18 were in its 16-wave pop loop).
// ---------------------------------------------------------------------------
__global__ __launch_bounds__(1024) void select_kernel(
    const unsigned short*     __restrict__ counts,  // [NGT][NXB]
    const unsigned long long* __restrict__ bucket,  // [NGT][NXB][SCAP]
    const float* __restrict__ pts,                  // [NPTS][2]
    const float* __restrict__ gtb,                  // [NGT][4]
    float* __restrict__ w)                          // [NPTS]
{
    const int g    = blockIdx.x;
    const int t    = threadIdx.x;
    const int lane = t & 63;
    const int wid  = t >> 6;                        // 16 waves

    __shared__ unsigned short scnt[NXB];            // 512 B
    __shared__ unsigned long long wl[16 * TOPK];    // 144 partial keys
    __shared__ unsigned tidx[TOPK];
    __shared__ float ppy[TOPK], ppx[TOPK];

    if (t < NXB) scnt[t] = counts[(size_t)g * NXB + t];
    __syncthreads();

    // ---- phase A: per-wave scan + pop-argmax (no barriers) ----
    const unsigned long long* src =
        bucket + (size_t)g * (NXB * SCAP) + (size_t)wid * 1024;

    unsigned long long e[16];
#pragma unroll
    for (int k = 0; k < 16; k += 4) {
        unsigned long long v[4];
#pragma unroll
        for (int j = 0; j < 4; ++j) v[j] = src[(k + j) * 64 + lane]; // coalesced
#pragma unroll
        for (int j = 0; j < 4; ++j) {
            int c = (int)scnt[wid * 16 + k + j];    // wave-uniform broadcast
            e[k + j] = (lane < c) ? v[j] : 0ULL;    // poison masked
        }
    }
    unsigned long long mymax = 0ULL;
#pragma unroll
    for (int j = 0; j < 16; ++j) mymax = umax64(mymax, e[j]);

#pragma unroll
    for (int r = 0; r < TOPK; ++r) {
        unsigned long long m = wave_max64(mymax);
        if (lane == 0) wl[wid * TOPK + r] = m;
        if (m != 0ULL && mymax == m) {              // unique owner pops
#pragma unroll
            for (int j = 0; j < 16; ++j) if (e[j] == m) e[j] = 0ULL;
            mymax = 0ULL;
#pragma unroll
            for (int j = 0; j < 16; ++j) mymax = umax64(mymax, e[j]);
        }
    }
    __syncthreads();

    // ---- phase B: wave 0 merges 144 partials + 9 fillers ----
    if (wid == 0) {
        unsigned long long f[4];
        f[0] = wl[lane];
        f[1] = wl[64 + lane];
        f[2] = (lane < 16) ? wl[128 + lane] : 0ULL;
        f[3] = (lane < TOPK) ? pack_key(-INFINITY, (unsigned)lane) : 0ULL;

        unsigned long long mx = 0ULL;
#pragma unroll
        for (int j = 0; j < 4; ++j) mx = umax64(mx, f[j]);

#pragma unroll
        for (int r = 0; r < TOPK; ++r) {
            unsigned long long m = wave_max64(mx);  // >0: fillers guarantee 9
            if (lane == 0) tidx[r] = ~(unsigned)(m & 0xFFFFFFFFu);
            if (mx == m) {                          // unique owner pops
#pragma unroll
                for (int j = 0; j < 4; ++j) if (f[j] == m) f[j] = 0ULL;
                mx = 0ULL;
#pragma unroll
                for (int j = 0; j < 4; ++j) mx = umax64(mx, f[j]);
            }
        }
    }
    __syncthreads();

    if (t < TOPK) {
        unsigned pi = tidx[t];
        ppy[t] = pts[2 * (size_t)pi];       // points col 0 ("cy" in reference)
        ppx[t] = pts[2 * (size_t)pi + 1];   // points col 1 ("cx")
    }
    __syncthreads();

    if (t == 0) {
        float4 g4 = ((const float4*)gtb)[g];
        float m0 = 0.0f, m1 = 0.0f;
#pragma unroll
        for (int k = 0; k < TOPK; ++k) { m0 += ppy[k]; m1 += ppx[k]; }
        m0 /= (float)TOPK; m1 /= (float)TOPK;

        float d0[TOPK], d1[TOPK];
        float a = 0.0f, bb = 0.0f, dd = 0.0f;
#pragma unroll
        for (int k = 0; k < TOPK; ++k) {
            d0[k] = ppy[k] - m0;
            d1[k] = ppx[k] - m1;
            a  += d0[k] * d0[k];
            bb += d0[k] * d1[k];
            dd += d1[k] * d1[k];
        }
        a /= (float)TOPK; bb /= (float)TOPK; dd /= (float)TOPK;
        float det  = a * dd - bb * bb;
        float rinv = 1.0f / (det + 1e-10f);

#pragma unroll
        for (int k = 0; k < TOPK; ++k) {
            float q = d0[k] * (dd * d0[k] - bb * d1[k])
                    + d1[k] * (a  * d1[k] - bb * d0[k]);
            float maha = q * rinv;
            float wt = expf(-0.5f * maha);
            bool valid = (ppx[k] - g4.x > 1e-10f) && (ppy[k] - g4.y > 1e-10f) &&
                         (g4.z - ppx[k] > 1e-10f) && (g4.w - ppy[k] > 1e-10f);
            float wv = valid ? wt : 0.0f;
            atomicMax((int*)&w[tidx[k]], __float_as_int(wv));
        }
    }
}

// ---------------------------------------------------------------------------
extern "C" void kernel_launch(void* const* d_in, const int* in_sizes, int n_in,
                              void* d_out, int out_size, void* d_ws, size_t ws_size,
                              hipStream_t stream) {
    const float* points  = (const float*)d_in[0];   // [65536,2]
    const float* cls     = (const float*)d_in[1];   // [65536,80]
    const float* preds   = (const float*)d_in[2];   // [65536,4]
    const float* gtb     = (const float*)d_in[3];   // [256,4]
    const int*   glab    = (const int*)d_in[4];     // [256]
    float* w = (float*)d_out;                       // [65536] f32

    char* ws = (char*)d_ws;
    unsigned long long* bucket = (unsigned long long*)ws;          // 33.55 MB
    size_t off = (size_t)NGT * NXB * SCAP * sizeof(unsigned long long);
    unsigned short* counts = (unsigned short*)(ws + off);          // 128 KB

    filter_kernel<<<dim3(NXB, NGT / GSLICE), 256, 0, stream>>>(
        preds, gtb, glab, cls, counts, bucket, w);
    select_kernel<<<NGT, 1024, 0, stream>>>(counts, bucket, points, gtb, w);
}